// Round 2
// baseline (2682.522 us; speedup 1.0000x reference)
//
#include <hip/hip_runtime.h>

#define Bb 8
#define Nn 2500
#define Ee 100
#define Ff 50
#define Yy 8922
#define Kk 9
#define YT 10          // y-rows per block in attention kernel (1 wave per row)
#define NCH 625        // Nn/4 float4 chunks

// ---------------------------------------------------------------------------
// Kernel 1: embedding lookup + conv1d (SAME, K=9) + tanh
// w read via wave-uniform s_load from convW (scalar pipe) — no LDS broadcasts
// ---------------------------------------------------------------------------
__global__ __launch_bounds__(256)
void conv_kernel(const int* __restrict__ x, const float* __restrict__ embW,
                 const float* __restrict__ convW, const float* __restrict__ convB,
                 float* __restrict__ h, float* __restrict__ h_t)
{
    __shared__ __align__(16) float emb_s[72 * 101];   // 72 rows (64 + 8 halo), pad 101

    const int b  = blockIdx.y;
    const int n0 = blockIdx.x * 64;
    const int t  = threadIdx.x;

    // stage embedding rows n0-4 .. n0+67 (zero outside [0,N))
    for (int idx = t; idx < 72 * Ee; idx += 256) {
        int r = idx / Ee, c = idx - r * Ee;
        int n = n0 - 4 + r;
        float v = 0.0f;
        if (n >= 0 && n < Nn) v = embW[(size_t)x[b * Nn + n] * Ee + c];
        emb_s[r * 101 + c] = v;
    }
    __syncthreads();

    const int nl = t & 63;                                   // n within tile
    const int g  = __builtin_amdgcn_readfirstlane(t >> 6);   // wave-uniform f-group

    float acc[13];
#pragma unroll
    for (int j = 0; j < 13; ++j) acc[j] = 0.0f;

    for (int e = 0; e < Ee; ++e) {
        float em[Kk];
#pragma unroll
        for (int k = 0; k < Kk; ++k) em[k] = emb_s[(nl + k) * 101 + e];
#pragma unroll
        for (int j = 0; j < 13; ++j) {
            int f = g * 13 + j;
            int fc = (f < Ff) ? f : (Ff - 1);                // uniform, clamped (no OOB)
            const float* wp = convW + ((size_t)fc * Ee + e) * Kk;   // uniform -> s_load
#pragma unroll
            for (int k = 0; k < Kk; ++k) acc[j] += em[k] * wp[k];
        }
    }

    const int n = n0 + nl;
    if (n < Nn) {
#pragma unroll
        for (int j = 0; j < 13; ++j) {
            int f = g * 13 + j;
            if (f < Ff) {
                float v = tanhf(acc[j] + convB[f]);
                h  [((size_t)b * Nn + n) * Ff + f] = v;
                h_t[((size_t)b * Ff + f) * Nn + n] = v;
            }
        }
    }
}

// ---------------------------------------------------------------------------
// Kernel 2: per-label attention, YT=10 rows/block, 640 threads (10 waves)
//   P1: scores into LDS; U read uniform (scalar pipe), h_t float4 (vmem)
//   P2: softmax per row (wave-owned), alpha -> global ONLY (no LDS writeback)
//   P3: pool from global alpha (uniform broadcast loads, aligned window n>=3)
//   P4: reduce strips + alpha edge terms (n=0,1,2,2499), logits, sigmoid
// ---------------------------------------------------------------------------
#define FMA4(A, HV, U) { A.x += HV.x*(U); A.y += HV.y*(U); A.z += HV.z*(U); A.w += HV.w*(U); }

__global__ __launch_bounds__(640)
void attn_kernel(const float* __restrict__ h, const float* __restrict__ h_t,
                 const float* __restrict__ U_w, const float* __restrict__ fin,
                 const float* __restrict__ finb, float* __restrict__ out)
{
    __shared__ __align__(16) float sc[YT * Nn];           // 100000 B score rows
    __shared__ __align__(16) float m_buf[YT * YT * 64];   // [strip][y][lane] partials

    const int b  = blockIdx.y;
    const int y0 = blockIdx.x * YT;
    const int t  = threadIdx.x;
    const int l  = t & 63;
    const int w  = __builtin_amdgcn_readfirstlane(t >> 6);  // wave id 0..9 (uniform)

    float* const abase = out + (size_t)Bb * Yy + 1;         // alpha region base

    // ---- Phase 1: scores[j][n4..n4+3] for all 10 j, one n-chunk per thread ----
    if (t < NCH) {
        const int n4 = t * 4;
        const float* hp = h_t + (size_t)b * Ff * Nn + n4;
        float4 a[YT];
#pragma unroll
        for (int j = 0; j < YT; ++j) a[j] = make_float4(0.f, 0.f, 0.f, 0.f);

        // uniform row bases for U (clamped for tail block)
        const float2* ub[YT];
#pragma unroll
        for (int j = 0; j < YT; ++j) {
            int yc = y0 + j; if (yc > Yy - 1) yc = Yy - 1;
            ub[j] = (const float2*)(U_w + (size_t)yc * Ff);
        }
#pragma unroll 2
        for (int fi = 0; fi < Ff / 2; ++fi) {
            float4 hv0 = *(const float4*)(hp);
            float4 hv1 = *(const float4*)(hp + Nn);
            hp += 2 * Nn;
#pragma unroll
            for (int j = 0; j < YT; ++j) {
                float2 uv = ub[j][fi];                       // uniform -> s_load
                FMA4(a[j], hv0, uv.x);
                FMA4(a[j], hv1, uv.y);
            }
        }
#pragma unroll
        for (int j = 0; j < YT; ++j)
            *(float4*)&sc[j * Nn + n4] = a[j];
    }
    __syncthreads();

    // ---- Phase 2: softmax of row w (one wave per row), alpha -> global ----
    {
        const int y = y0 + w;
        const bool valid = (y < Yy);
        float4 v[10];
        float M = -3.0e38f;
#pragma unroll
        for (int i = 0; i < 10; ++i) {
            int c = l + 64 * i;
            if (c < NCH) {
                v[i] = *(const float4*)&sc[w * Nn + c * 4];
                M = fmaxf(M, fmaxf(fmaxf(v[i].x, v[i].y), fmaxf(v[i].z, v[i].w)));
            }
        }
#pragma unroll
        for (int o = 32; o > 0; o >>= 1) M = fmaxf(M, __shfl_xor(M, o));
        float S = 0.0f;
#pragma unroll
        for (int i = 0; i < 10; ++i) {
            int c = l + 64 * i;
            if (c < NCH) {
                v[i].x = __expf(v[i].x - M); v[i].y = __expf(v[i].y - M);
                v[i].z = __expf(v[i].z - M); v[i].w = __expf(v[i].w - M);
                S += (v[i].x + v[i].y) + (v[i].z + v[i].w);
            }
        }
#pragma unroll
        for (int o = 32; o > 0; o >>= 1) S += __shfl_xor(S, o);
        const float inv = 1.0f / S;
        float* ag = abase + ((size_t)b * Yy + y) * (size_t)Nn;
#pragma unroll
        for (int i = 0; i < 10; ++i) {
            int c = l + 64 * i;
            if (c < NCH && valid) {
                const int n = c * 4;
                ag[n]     = v[i].x * inv;
                ag[n + 1] = v[i].y * inv;
                ag[n + 2] = v[i].z * inv;
                ag[n + 3] = v[i].w * inv;
            }
        }
    }
    __syncthreads();   // drains vmcnt: alpha stores visible to this block's reads

    // ---- Phase 3: m[j][f] partials over aligned window n = 3 + 4*qi ----
    const int jmax = (Yy - y0 < YT) ? (Yy - y0) : YT;
    const float* hbn = h + (size_t)b * Nn * Ff;
    float m[YT];
#pragma unroll
    for (int j = 0; j < YT; ++j) m[j] = 0.0f;

    {
        // uniform alpha row pointers (clamped rows for tail; results unused)
        const float* ar[YT];
#pragma unroll
        for (int j = 0; j < YT; ++j) {
            int jc = (j < jmax) ? j : (jmax - 1);
            ar[j] = abase + ((size_t)b * Yy + y0 + jc) * (size_t)Nn;
        }
        if (l < Ff) {
            for (int qi = w; qi < 624; qi += YT) {
                const int n4 = 3 + qi * 4;                       // 16B-aligned in out
                const float* hp = hbn + (size_t)n4 * Ff + l;
                float h0 = hp[0], h1 = hp[Ff], h2 = hp[2 * Ff], h3 = hp[3 * Ff];
#pragma unroll
                for (int j = 0; j < YT; ++j) {
                    float4 av = *(const float4*)(ar[j] + n4);    // uniform broadcast
                    m[j] += av.x * h0 + av.y * h1 + av.z * h2 + av.w * h3;
                }
            }
        }
    }
#pragma unroll
    for (int j = 0; j < YT; ++j) m_buf[(w * YT + j) * 64 + l] = m[j];
    __syncthreads();

    // ---- Phase 4: reduce strips + edge terms (n=0,1,2,2499), logits ----
    {
        float s = 0.0f;
#pragma unroll
        for (int ww = 0; ww < YT; ++ww) s += m_buf[(ww * YT + w) * 64 + l];
        const int y = y0 + w;
        const bool act = (l < Ff) && (y < Yy);
        if (act) {
            const float* arw = abase + ((size_t)b * Yy + y) * (size_t)Nn;
            float a0 = arw[0], a1 = arw[1], a2 = arw[2], a3 = arw[Nn - 1];
            s += a0 * hbn[0 * Ff + l] + a1 * hbn[1 * Ff + l]
               + a2 * hbn[2 * Ff + l] + a3 * hbn[(size_t)(Nn - 1) * Ff + l];
        }
        float p = act ? s * fin[y * Ff + l] : 0.0f;
#pragma unroll
        for (int o = 32; o > 0; o >>= 1) p += __shfl_xor(p, o);
        if (l == 0 && y < Yy) {
            out[b * Yy + y] = 1.0f / (1.0f + __expf(-(p + finb[y])));
        }
    }
}

// ---------------------------------------------------------------------------
// Kernel 3: BCE loss (mean) over yhat (already in out[0..B*Y)) vs target
// ---------------------------------------------------------------------------
__global__ __launch_bounds__(1024)
void loss_kernel(const float* __restrict__ target, float* __restrict__ out)
{
    __shared__ float red[16];
    const int t = threadIdx.x;
    float acc = 0.0f;
    for (int i = t; i < Bb * Yy; i += 1024) {
        float p = out[i];
        p = fminf(fmaxf(p, 1e-7f), 1.0f - 1e-7f);
        float tg = target[i];
        acc += tg * logf(p) + (1.0f - tg) * log1pf(-p);
    }
#pragma unroll
    for (int o = 32; o > 0; o >>= 1) acc += __shfl_xor(acc, o);
    if ((t & 63) == 0) red[t >> 6] = acc;
    __syncthreads();
    if (t == 0) {
        float s = 0.0f;
#pragma unroll
        for (int i = 0; i < 16; ++i) s += red[i];
        out[Bb * Yy] = -s / (float)(Bb * Yy);
    }
}

// ---------------------------------------------------------------------------
extern "C" void kernel_launch(void* const* d_in, const int* in_sizes, int n_in,
                              void* d_out, int out_size, void* d_ws, size_t ws_size,
                              hipStream_t stream)
{
    const int*   x      = (const int*)  d_in[0];
    const float* target = (const float*)d_in[1];
    const float* embW   = (const float*)d_in[2];
    const float* convW  = (const float*)d_in[3];
    const float* convB  = (const float*)d_in[4];
    const float* U_w    = (const float*)d_in[5];
    const float* fin    = (const float*)d_in[6];
    const float* finb   = (const float*)d_in[7];
    float* out = (float*)d_out;
    float* h   = (float*)d_ws;                                    // 4 MB: h[b][n][f]
    float* h_t = (float*)((char*)d_ws + (size_t)4 * 1024 * 1024); // 4 MB: h_t[b][f][n]

    dim3 g1((Nn + 63) / 64, Bb);
    conv_kernel<<<g1, dim3(256), 0, stream>>>(x, embW, convW, convB, h, h_t);

    dim3 g2((Yy + YT - 1) / YT, Bb);
    attn_kernel<<<g2, dim3(640), 0, stream>>>(h, h_t, U_w, fin, finb, out);

    loss_kernel<<<dim3(1), dim3(1024), 0, stream>>>(target, out);
}